// Round 1
// baseline (988.138 us; speedup 1.0000x reference)
//
#include <hip/hip_runtime.h>

#define NDIM  2048
#define WAVES 32
#define BCOLS 2176            // 0..2048 valid + pad
#define PADF  4096
#define PADB  4096
#define ENCB  0x40000000
#define SENTV 0xFFFFFFFFFFFFFFFFull

typedef unsigned long long u64;

// Static scratch: no dependence on ws_size. Zero-init at load; prep kernel
// rewrites everything it relies on, every launch (graph-replay safe).
__device__ __align__(16) float g_T[PADF + NDIM*NDIM*3 + PADB];   // exp(theta), padded
__device__ __align__(16) u64   g_B[(size_t)(WAVES+1) * BCOLS * 2]; // boundary handoff

__device__ __forceinline__ u64 ald(const u64* p) {
  return __hip_atomic_load(p, __ATOMIC_RELAXED, __HIP_MEMORY_SCOPE_AGENT);
}
__device__ __forceinline__ void ast(u64* p, u64 v) {
  __hip_atomic_store(p, v, __ATOMIC_RELAXED, __HIP_MEMORY_SCOPE_AGENT);
}

// ---------------- prep: exp(theta) + sentinel/boundary init ----------------
__global__ void vit_prep(const float* __restrict__ theta) {
  const int tid = blockIdx.x * blockDim.x + threadIdx.x;
  const int stride = gridDim.x * blockDim.x;
  const int n4 = (NDIM*NDIM*3) / 4;
  const float4* src = (const float4*)theta;
  float4* dst = (float4*)(g_T + PADF);
  for (int i = tid; i < n4; i += stride) {
    float4 v = src[i];
    float4 r;
    r.x = __expf(v.x); r.y = __expf(v.y); r.z = __expf(v.z); r.w = __expf(v.w);
    dst[i] = r;
  }
  const int nb = (WAVES+1) * BCOLS;
  const u64 hi0 = ((u64)(unsigned)ENCB) << 32;   // (Y=0, e_enc=ENCB i.e. e=0)
  for (int i = tid; i < nb; i += stride) {
    int w = i / BCOLS;
    int c = i - w * BCOLS;
    u64 lo, hi;
    if (c > NDIM)    { lo = 0ull; hi = hi0; }                                   // pad cols: zeros
    else if (w == 0) { lo = (c == 0) ? (u64)__float_as_uint(1.0f) : 0ull; hi = hi0; } // row 0: V[0,0]=(0,-inf,-inf)
    else if (c == 0) { lo = 0ull; hi = hi0; }                                   // V[i,0] = -inf
    else             { lo = SENTV; hi = SENTV; }                                // to be produced
    ast(&g_B[(size_t)i*2],   lo);
    ast(&g_B[(size_t)i*2+1], hi);
  }
}

// ---------------- main: 32 waves, striped wavefront, exp-space -------------
__global__ void __launch_bounds__(64) vit_main(const float* __restrict__ A,
                                               float* __restrict__ out) {
  const int lane = threadIdx.x;
  const int w    = blockIdx.x;
  const bool isL0 = (lane == 0);

  const float a00 = __expf(A[0]), a01 = __expf(A[1]), a02 = __expf(A[2]);
  const float a10 = __expf(A[3]), a11 = __expf(A[4]), a12 = __expf(A[5]);
  const float a20 = __expf(A[6]), a21 = __expf(A[7]), a22 = __expf(A[8]);

  const float* tbase = g_T + PADF + (size_t)(w*64 + lane) * (NDIM*3);
  u64* bin  = g_B + (size_t)w     * BCOLS * 2;
  u64* bout = g_B + (size_t)(w+1) * BCOLS * 2;

  // state: own row col j-1 (p), row-above col j (u), row-above col j-1 (ud)
  float Mp=0.f,Xp=0.f,Yp=0.f, Mu=0.f,Xu=0.f,Yu=0.f, Mud=0.f,Xud=0.f,Yud=0.f;
  int e_w = 0;  // wave scale: registers hold value * 2^-e_w

  // theta prefetch ring: slot u holds col (s-1-lane) for s=u+1
  float t0[16], t1[16], t2[16];
  #pragma unroll
  for (int u = 0; u < 16; ++u) {
    const float* ta = tbase + (u - lane)*3;
    t0[u] = ta[0]; t1[u] = ta[1]; t2[u] = ta[2];
  }
  // boundary prefetch ring: cols 2..17
  u64 rLo[16], rHi[16];
  #pragma unroll
  for (int c = 2; c <= 17; ++c) {
    rLo[c & 15] = ald(bin + (size_t)c*2);
    rHi[c & 15] = ald(bin + (size_t)c*2 + 1);
  }
  // col 0 -> ud (prefilled, never sentinel)
  {
    u64 lo = ald(bin), hi = ald(bin + 1);
    while (lo == SENTV || hi == SENTV) { __builtin_amdgcn_s_sleep(2); lo = ald(bin); hi = ald(bin+1); }
    if (isL0) {
      Mud = __uint_as_float((unsigned)lo);
      Xud = __uint_as_float((unsigned)(lo >> 32));
      Yud = __uint_as_float((unsigned)hi);
    }
  }
  // col 1 -> u (spin = pipeline fill)
  {
    u64 lo = ald(bin + 2), hi = ald(bin + 3);
    while (lo == SENTV || hi == SENTV) { __builtin_amdgcn_s_sleep(8); lo = ald(bin+2); hi = ald(bin+3); }
    int ep = (int)((unsigned)(hi >> 32) - (unsigned)ENCB);
    int dd = ep - e_w;
    if (__builtin_amdgcn_readfirstlane(dd) > 48) { e_w = ep; dd = 0; } // states are zero
    if (isL0) {
      Mu = ldexpf(__uint_as_float((unsigned)lo), dd);
      Xu = ldexpf(__uint_as_float((unsigned)(lo >> 32)), dd);
      Yu = ldexpf(__uint_as_float((unsigned)hi), dd);
    }
  }

  for (int base = 0; base < 2112; base += 16) {
    const float* tA = tbase + (base + 16 - lane)*3;        // prefetch for s+16
    u64* bA = bin + (size_t)(base + 18)*2;                 // prefetch col s+17
    u64* bS = bin + (size_t)(base + 2)*2;                  // spin reload col s+1
    u64* bO = bout + (size_t)(base - 62)*2;                // store col s-63
    #pragma unroll
    for (int u = 0; u < 16; ++u) {
      const int s = base + u + 1;                          // lane computes col j = s - lane
      const float T0 = t0[u], T1 = t1[u], T2 = t2[u];
      float mn = T0 * fmaf(a02, Yud, fmaf(a01, Xud, a00*Mud));
      float xn = T1 * fmaf(a12, Yu,  fmaf(a11, Xu,  a10*Mu));
      float yn = T2 * fmaf(a22, Yp,  fmaf(a21, Xp,  a20*Mp));
      // producer handoff (lane 63 = wave's last row), cols 1..(2049 junk ok)
      if (s >= 64) {
        if (lane == 63) {
          u64 lo = ((u64)__float_as_uint(xn) << 32) | __float_as_uint(mn);
          u64 hi = ((u64)(unsigned)(e_w + ENCB) << 32) | __float_as_uint(yn);
          ast(bO + (size_t)u*2,     lo);
          ast(bO + (size_t)u*2 + 1, hi);
        }
      }
      // terminal: V[2048,2048] at wave 31, lane 63, s = 2048+63
      if (s == 2111) {
        if (w == 31 && lane == 63) {
          out[0] = (log2f(mn + xn + yn) + (float)e_w) * 0.69314718055994531f;
        }
      }
      // theta prefetch for s+16
      { const float* ta = tA + u*3; t0[u] = ta[0]; t1[u] = ta[1]; t2[u] = ta[2]; }
      // boundary consume for col s+1
      u64 lo = rLo[(u+2)&15], hi = rHi[(u+2)&15];
      if (lo == SENTV || hi == SENTV) {
        do { __builtin_amdgcn_s_sleep(2);
             lo = ald(bS + (size_t)u*2); hi = ald(bS + (size_t)u*2 + 1);
        } while (lo == SENTV || hi == SENTV);
      }
      const float Mb = __uint_as_float((unsigned)lo);
      const float Xb = __uint_as_float((unsigned)(lo >> 32));
      const float Yb = __uint_as_float((unsigned)hi);
      int d = (int)((unsigned)(hi >> 32) - (unsigned)ENCB) - e_w;
      if (__builtin_amdgcn_readfirstlane(d) > 48) {
        // producer's magnitude dwarfs ours: adopt its scale (values preserved)
        const int ep = (int)((unsigned)(hi >> 32) - (unsigned)ENCB);
        const int sh = e_w - ep;
        mn = ldexpf(mn,sh); xn = ldexpf(xn,sh); yn = ldexpf(yn,sh);
        Mu = ldexpf(Mu,sh); Xu = ldexpf(Xu,sh); Yu = ldexpf(Yu,sh);
        Mud= ldexpf(Mud,sh);Xud= ldexpf(Xud,sh);Yud= ldexpf(Yud,sh);
        e_w = ep; d = 0;
      }
      // boundary prefetch col s+17 into same slot
      rLo[(u+2)&15] = ald(bA + (size_t)u*2);
      rHi[(u+2)&15] = ald(bA + (size_t)u*2 + 1);
      // rotate
      Mud = Mu; Xud = Xu; Yud = Yu;
      const float sm = __shfl_up(mn, 1);
      const float sx = __shfl_up(xn, 1);
      const float sy = __shfl_up(yn, 1);
      Mu = isL0 ? ldexpf(Mb, d) : sm;
      Xu = isL0 ? ldexpf(Xb, d) : sx;
      Yu = isL0 ? ldexpf(Yb, d) : sy;
      Mp = mn; Xp = xn; Yp = yn;
    }
    // epoch rescale (wave-uniform, exact power-of-2)
    {
      float m = fmaxf(fmaxf(Mp, Xp), Yp);
      const int jl = base + 16 - lane;          // last computed column
      if (jl < 1 || jl > NDIM) m = 0.0f;        // exclude warmup/drain junk lanes
      #pragma unroll
      for (int off = 1; off < 64; off <<= 1) m = fmaxf(m, __shfl_xor(m, off));
      int E = (int)((__float_as_uint(m) >> 23) & 0xFF) - 127;
      if (m == 0.0f) E = 0;
      const int sh = -E;
      Mp = ldexpf(Mp,sh); Xp = ldexpf(Xp,sh); Yp = ldexpf(Yp,sh);
      Mu = ldexpf(Mu,sh); Xu = ldexpf(Xu,sh); Yu = ldexpf(Yu,sh);
      Mud= ldexpf(Mud,sh);Xud= ldexpf(Xud,sh);Yud= ldexpf(Yud,sh);
      e_w += E;
    }
  }
}

extern "C" void kernel_launch(void* const* d_in, const int* in_sizes, int n_in,
                              void* d_out, int out_size, void* d_ws, size_t ws_size,
                              hipStream_t stream) {
  const float* theta = (const float*)d_in[0];
  const float* A     = (const float*)d_in[1];
  float* out = (float*)d_out;
  (void)in_sizes; (void)n_in; (void)out_size; (void)d_ws; (void)ws_size;
  vit_prep<<<dim3(4096), dim3(256), 0, stream>>>(theta);
  vit_main<<<dim3(WAVES), dim3(64), 0, stream>>>(A, out);
}

// Round 2
// 869.242 us; speedup vs baseline: 1.1368x; 1.1368x over previous
//
#include <hip/hip_runtime.h>

#define NDIM  2048
#define WAVES 32
#define BCOLS 2176            // 0..2048 valid + pad
#define PADF  4096
#define PADB  4096
#define ENCB  0x40000000
#define SENTV 0xFFFFFFFFFFFFFFFFull

typedef unsigned long long u64;

// Static scratch: no dependence on ws_size. Prep kernel rewrites everything
// it relies on, every launch (graph-replay safe).
__device__ __align__(16) float g_T[PADF + NDIM*NDIM*3 + PADB];   // exp(theta), padded
__device__ __align__(16) u64   g_B[(size_t)(WAVES+1) * BCOLS * 2]; // boundary handoff

__device__ __forceinline__ u64 ald(const u64* p) {
  return __hip_atomic_load(p, __ATOMIC_RELAXED, __HIP_MEMORY_SCOPE_AGENT);
}
__device__ __forceinline__ void ast(u64* p, u64 v) {
  __hip_atomic_store(p, v, __ATOMIC_RELAXED, __HIP_MEMORY_SCOPE_AGENT);
}
// shift-up-by-1 across the wave via DPP wave_shr1 (VALU, no LDS latency).
// Lane 0 receives 0 (bound_ctrl old=0) and is overwritten by the boundary select.
__device__ __forceinline__ float shup1(float x) {
  int v = __builtin_amdgcn_update_dpp(0, __float_as_int(x), 0x138, 0xf, 0xf, false);
  return __int_as_float(v);
}

// ---------------- prep: exp(theta) + sentinel/boundary init ----------------
__global__ void vit_prep(const float* __restrict__ theta) {
  const int tid = blockIdx.x * blockDim.x + threadIdx.x;
  const int stride = gridDim.x * blockDim.x;
  const int n4 = (NDIM*NDIM*3) / 4;
  const float4* src = (const float4*)theta;
  float4* dst = (float4*)(g_T + PADF);
  for (int i = tid; i < n4; i += stride) {
    float4 v = src[i];
    float4 r;
    r.x = __expf(v.x); r.y = __expf(v.y); r.z = __expf(v.z); r.w = __expf(v.w);
    dst[i] = r;
  }
  const int nb = (WAVES+1) * BCOLS;
  const u64 hi0 = ((u64)(unsigned)ENCB) << 32;   // (Y=0, e_enc=ENCB i.e. e=0)
  for (int i = tid; i < nb; i += stride) {
    int w = i / BCOLS;
    int c = i - w * BCOLS;
    u64 lo, hi;
    if (c > NDIM)    { lo = 0ull; hi = hi0; }                                   // pad cols: zeros
    else if (w == 0) { lo = (c == 0) ? (u64)__float_as_uint(1.0f) : 0ull; hi = hi0; } // row 0
    else if (c == 0) { lo = 0ull; hi = hi0; }                                   // V[i,0] = -inf
    else             { lo = SENTV; hi = SENTV; }                                // to be produced
    ast(&g_B[(size_t)i*2],   lo);
    ast(&g_B[(size_t)i*2+1], hi);
  }
}

// ---------------- main: 32 waves, striped wavefront, exp-space -------------
__global__ void __launch_bounds__(64, 1) vit_main(const float* __restrict__ A,
                                                  float* __restrict__ out) {
  const int lane = threadIdx.x;
  const int w    = blockIdx.x;
  const bool isL0 = (lane == 0);

  const float a00 = __expf(A[0]), a01 = __expf(A[1]), a02 = __expf(A[2]);
  const float a10 = __expf(A[3]), a11 = __expf(A[4]), a12 = __expf(A[5]);
  const float a20 = __expf(A[6]), a21 = __expf(A[7]), a22 = __expf(A[8]);

  const float* tbase = g_T + PADF + (size_t)(w*64 + lane) * (NDIM*3);
  u64* bin  = g_B + (size_t)w     * BCOLS * 2;
  u64* bout = g_B + (size_t)(w+1) * BCOLS * 2;

  // state: own row col j-1 (p), row-above col j (u), row-above col j-1 (ud)
  float Mp=0.f,Xp=0.f,Yp=0.f, Mu=0.f,Xu=0.f,Yu=0.f, Mud=0.f,Xud=0.f,Yud=0.f;
  int e_w = 0;  // wave scale: registers hold value * 2^-e_w

  // theta prefetch ring (distance 16): slot u holds col (s-1-lane) for s=u+1
  float t0[16], t1[16], t2[16];
  #pragma unroll
  for (int u = 0; u < 16; ++u) {
    const float* ta = tbase + (u - lane)*3;
    t0[u] = ta[0]; t1[u] = ta[1]; t2[u] = ta[2];
  }
  // boundary prefetch ring (distance 4): cols 2..5
  u64 rLo[4], rHi[4];
  #pragma unroll
  for (int c = 2; c <= 5; ++c) {
    rLo[c & 3] = ald(bin + (size_t)c*2);
    rHi[c & 3] = ald(bin + (size_t)c*2 + 1);
  }
  // col 0 -> ud (prefilled, never sentinel)
  {
    u64 lo = ald(bin), hi = ald(bin + 1);
    while (lo == SENTV || hi == SENTV) { __builtin_amdgcn_s_sleep(2); lo = ald(bin); hi = ald(bin+1); }
    if (isL0) {
      Mud = __uint_as_float((unsigned)lo);
      Xud = __uint_as_float((unsigned)(lo >> 32));
      Yud = __uint_as_float((unsigned)hi);
    }
  }
  // col 1 -> u (spin = pipeline fill)
  {
    u64 lo = ald(bin + 2), hi = ald(bin + 3);
    while (lo == SENTV || hi == SENTV) { __builtin_amdgcn_s_sleep(8); lo = ald(bin+2); hi = ald(bin+3); }
    int ep = (int)((unsigned)(hi >> 32) - (unsigned)ENCB);
    int dd = ep - e_w;
    if (__builtin_amdgcn_readfirstlane(dd) > 48) { e_w = ep; dd = 0; } // states are zero
    if (isL0) {
      Mu = ldexpf(__uint_as_float((unsigned)lo), dd);
      Xu = ldexpf(__uint_as_float((unsigned)(lo >> 32)), dd);
      Yu = ldexpf(__uint_as_float((unsigned)hi), dd);
    }
  }

  for (int base = 0; base < 2112; base += 16) {
    const float* tA = tbase + (base + 16 - lane)*3;        // theta prefetch for s+16
    u64* bA = bin + (size_t)(base + 6)*2;                  // prefetch col s+5
    u64* bS = bin + (size_t)(base + 2)*2;                  // spin reload col s+1
    u64* bO = bout + (size_t)(base - 62)*2;                // store col s-63
    #pragma unroll
    for (int u = 0; u < 16; ++u) {
      const int s = base + u + 1;                          // lane computes col j = s - lane
      const float T0 = t0[u], T1 = t1[u], T2 = t2[u];
      float mn = T0 * fmaf(a02, Yud, fmaf(a01, Xud, a00*Mud));
      float xn = T1 * fmaf(a12, Yu,  fmaf(a11, Xu,  a10*Mu));
      float yn = T2 * fmaf(a22, Yp,  fmaf(a21, Xp,  a20*Mp));
      // producer handoff (lane 63 = wave's last row)
      if (s >= 64) {
        if (lane == 63) {
          u64 lo = ((u64)__float_as_uint(xn) << 32) | __float_as_uint(mn);
          u64 hi = ((u64)(unsigned)(e_w + ENCB) << 32) | __float_as_uint(yn);
          ast(bO + (size_t)u*2,     lo);
          ast(bO + (size_t)u*2 + 1, hi);
        }
      }
      // terminal: V[2048,2048] at wave 31, lane 63, s = 2111
      if (s == 2111) {
        if (w == 31 && lane == 63) {
          out[0] = (log2f(mn + xn + yn) + (float)e_w) * 0.69314718055994531f;
        }
      }
      // theta prefetch for s+16
      { const float* ta = tA + u*3; t0[u] = ta[0]; t1[u] = ta[1]; t2[u] = ta[2]; }
      // boundary consume for col s+1 (slot (u+2)&3)
      u64 lo = rLo[(u+2)&3], hi = rHi[(u+2)&3];
      if (lo == SENTV || hi == SENTV) {
        do { __builtin_amdgcn_s_sleep(2);
             lo = ald(bS + (size_t)u*2); hi = ald(bS + (size_t)u*2 + 1);
        } while (lo == SENTV || hi == SENTV);
      }
      const float Mb = __uint_as_float((unsigned)lo);
      const float Xb = __uint_as_float((unsigned)(lo >> 32));
      const float Yb = __uint_as_float((unsigned)hi);
      int d = (int)((unsigned)(hi >> 32) - (unsigned)ENCB) - e_w;
      if (__builtin_amdgcn_readfirstlane(d) > 48) {
        // producer's magnitude dwarfs ours: adopt its scale
        const int ep = (int)((unsigned)(hi >> 32) - (unsigned)ENCB);
        const int sh = e_w - ep;
        mn = ldexpf(mn,sh); xn = ldexpf(xn,sh); yn = ldexpf(yn,sh);
        Mu = ldexpf(Mu,sh); Xu = ldexpf(Xu,sh); Yu = ldexpf(Yu,sh);
        Mud= ldexpf(Mud,sh);Xud= ldexpf(Xud,sh);Yud= ldexpf(Yud,sh);
        e_w = ep; d = 0;
      }
      // boundary prefetch col s+5 into the slot just consumed
      rLo[(u+2)&3] = ald(bA + (size_t)u*2);
      rHi[(u+2)&3] = ald(bA + (size_t)u*2 + 1);
      // rotate
      Mud = Mu; Xud = Xu; Yud = Yu;
      const float sm = shup1(mn);
      const float sx = shup1(xn);
      const float sy = shup1(yn);
      Mu = isL0 ? ldexpf(Mb, d) : sm;
      Xu = isL0 ? ldexpf(Xb, d) : sx;
      Yu = isL0 ? ldexpf(Yb, d) : sy;
      Mp = mn; Xp = xn; Yp = yn;
    }
    // epoch rescale (wave-uniform, exact power-of-2)
    {
      float m = fmaxf(fmaxf(Mp, Xp), Yp);
      const int jl = base + 16 - lane;          // last computed column
      if (jl < 1 || jl > NDIM) m = 0.0f;        // exclude warmup/drain junk lanes
      #pragma unroll
      for (int off = 1; off < 64; off <<= 1) m = fmaxf(m, __shfl_xor(m, off));
      int E = (int)((__float_as_uint(m) >> 23) & 0xFF) - 127;
      if (m == 0.0f) E = 0;
      const int sh = -E;
      Mp = ldexpf(Mp,sh); Xp = ldexpf(Xp,sh); Yp = ldexpf(Yp,sh);
      Mu = ldexpf(Mu,sh); Xu = ldexpf(Xu,sh); Yu = ldexpf(Yu,sh);
      Mud= ldexpf(Mud,sh);Xud= ldexpf(Xud,sh);Yud= ldexpf(Yud,sh);
      e_w += E;
    }
  }
}

extern "C" void kernel_launch(void* const* d_in, const int* in_sizes, int n_in,
                              void* d_out, int out_size, void* d_ws, size_t ws_size,
                              hipStream_t stream) {
  const float* theta = (const float*)d_in[0];
  const float* A     = (const float*)d_in[1];
  float* out = (float*)d_out;
  (void)in_sizes; (void)n_in; (void)out_size; (void)d_ws; (void)ws_size;
  vit_prep<<<dim3(4096), dim3(256), 0, stream>>>(theta);
  vit_main<<<dim3(WAVES), dim3(64), 0, stream>>>(A, out);
}